// Round 1
// baseline (419.122 us; speedup 1.0000x reference)
//
#include <hip/hip_runtime.h>

// Problem constants (GraphConvolution_71923522339430)
#define D_IN  128
#define D_OUT 64

// ---------------------------------------------------------------------------
// Kernel 1: h = x @ W   ([N,128] @ [128,64] -> [N,64], f32)
// Block = 256 threads, 64 nodes per block.
// LDS: Xs[64][132] (pad->conflict-free broadcast reads), Ws[128][68] ([k][d]
// layout so the 16 dim-lanes read contiguous float4s -> conflict-free).
// Thread (tx,ty): tx in [0,16) owns dims tx*4..+3; ty in [0,16) owns nodes
// ty*4..+3. 4x4 register tile, float4 FMAs.
// ---------------------------------------------------------------------------
__global__ __launch_bounds__(256) void gemm_h_kernel(
    const float* __restrict__ x, const float* __restrict__ w,
    float* __restrict__ h, int n_nodes)
{
    __shared__ float Xs[64 * 132];   // 33792 B
    __shared__ float Ws[128 * 68];   // 34816 B

    const int t   = threadIdx.x;
    const int tx  = t & 15;          // dim group
    const int ty  = t >> 4;          // node group
    const int node0 = blockIdx.x * 64;

    // Stage W: 2048 float4, 8 per thread. Coalesced global, aligned LDS.
    for (int j = 0; j < 8; ++j) {
        int idx = j * 256 + t;           // float4 index
        int k   = idx >> 4;              // row (16 float4 per 64-float row)
        int c   = idx & 15;              // float4 col
        float4 v = *(const float4*)&w[k * D_OUT + c * 4];
        *(float4*)&Ws[k * 68 + c * 4] = v;
    }
    // Stage X tile: 64 rows x 128 floats = 2048 float4, 8 per thread.
    for (int j = 0; j < 8; ++j) {
        int idx = j * 256 + t;
        int r   = idx >> 5;              // node row (32 float4 per row)
        int c   = idx & 31;
        int gn  = node0 + r;
        float4 v = make_float4(0.f, 0.f, 0.f, 0.f);
        if (gn < n_nodes) v = *(const float4*)&x[(size_t)gn * D_IN + c * 4];
        *(float4*)&Xs[r * 132 + c * 4] = v;
    }
    __syncthreads();

    float4 acc[4];
    for (int i = 0; i < 4; ++i) acc[i] = make_float4(0.f, 0.f, 0.f, 0.f);

    const int d0 = tx * 4;
    const int n0 = ty * 4;

    #pragma unroll
    for (int k = 0; k < D_IN; k += 4) {
        float4 xa[4], wb[4];
        #pragma unroll
        for (int i = 0; i < 4; ++i)
            xa[i] = *(const float4*)&Xs[(n0 + i) * 132 + k];
        #pragma unroll
        for (int r = 0; r < 4; ++r)
            wb[r] = *(const float4*)&Ws[(k + r) * 68 + d0];
        #pragma unroll
        for (int i = 0; i < 4; ++i) {
            acc[i].x = fmaf(xa[i].x, wb[0].x, acc[i].x);
            acc[i].y = fmaf(xa[i].x, wb[0].y, acc[i].y);
            acc[i].z = fmaf(xa[i].x, wb[0].z, acc[i].z);
            acc[i].w = fmaf(xa[i].x, wb[0].w, acc[i].w);
            acc[i].x = fmaf(xa[i].y, wb[1].x, acc[i].x);
            acc[i].y = fmaf(xa[i].y, wb[1].y, acc[i].y);
            acc[i].z = fmaf(xa[i].y, wb[1].z, acc[i].z);
            acc[i].w = fmaf(xa[i].y, wb[1].w, acc[i].w);
            acc[i].x = fmaf(xa[i].z, wb[2].x, acc[i].x);
            acc[i].y = fmaf(xa[i].z, wb[2].y, acc[i].y);
            acc[i].z = fmaf(xa[i].z, wb[2].z, acc[i].z);
            acc[i].w = fmaf(xa[i].z, wb[2].w, acc[i].w);
            acc[i].x = fmaf(xa[i].w, wb[3].x, acc[i].x);
            acc[i].y = fmaf(xa[i].w, wb[3].y, acc[i].y);
            acc[i].z = fmaf(xa[i].w, wb[3].z, acc[i].z);
            acc[i].w = fmaf(xa[i].w, wb[3].w, acc[i].w);
        }
    }

    #pragma unroll
    for (int i = 0; i < 4; ++i) {
        int gn = node0 + n0 + i;
        if (gn < n_nodes)
            *(float4*)&h[(size_t)gn * D_OUT + d0] = acc[i];
    }
}

// ---------------------------------------------------------------------------
// Kernel 2: build CSR row_ptr from sorted edge_dst.
// row_ptr[j] = first edge index with dst >= j; row_ptr[N] = E.
// ---------------------------------------------------------------------------
__global__ __launch_bounds__(256) void build_row_ptr_kernel(
    const int* __restrict__ dst, int* __restrict__ row_ptr, int n_edges, int n_nodes)
{
    int e = blockIdx.x * blockDim.x + threadIdx.x;
    if (e >= n_edges) return;
    int d1 = dst[e];
    int d0 = (e == 0) ? -1 : dst[e - 1];
    for (int j = d0 + 1; j <= d1; ++j) row_ptr[j] = e;
    if (e == n_edges - 1) {
        for (int j = d1 + 1; j <= n_nodes; ++j) row_ptr[j] = n_edges;
    }
}

// ---------------------------------------------------------------------------
// Kernel 3: out[i][d] = bias[d] + sum_{e in [row_ptr[i],row_ptr[i+1])}
//                       vals[e] * h[src[e]][d]
// One wave (64 lanes == D_OUT) per node. Broadcast src/val loads (uniform
// address), coalesced 256B h-row loads. 2x unroll for memory-level parallelism.
// ---------------------------------------------------------------------------
__global__ __launch_bounds__(256) void aggregate_kernel(
    const float* __restrict__ h, const int* __restrict__ src,
    const float* __restrict__ vals, const int* __restrict__ row_ptr,
    const float* __restrict__ bias, float* __restrict__ out, int n_nodes)
{
    int wave = (blockIdx.x * blockDim.x + threadIdx.x) >> 6;
    int lane = threadIdx.x & 63;
    if (wave >= n_nodes) return;

    int b = row_ptr[wave];
    int e = row_ptr[wave + 1];

    float acc = 0.f;
    int k = b;
    for (; k + 1 < e; k += 2) {
        int   s0 = src[k],    s1 = src[k + 1];
        float v0 = vals[k],   v1 = vals[k + 1];
        float h0 = h[(size_t)s0 * D_OUT + lane];
        float h1 = h[(size_t)s1 * D_OUT + lane];
        acc = fmaf(v0, h0, acc);
        acc = fmaf(v1, h1, acc);
    }
    if (k < e) {
        int   s0 = src[k];
        float v0 = vals[k];
        acc = fmaf(v0, h[(size_t)s0 * D_OUT + lane], acc);
    }

    out[(size_t)wave * D_OUT + lane] = acc + bias[lane];
}

// ---------------------------------------------------------------------------
extern "C" void kernel_launch(void* const* d_in, const int* in_sizes, int n_in,
                              void* d_out, int out_size, void* d_ws, size_t ws_size,
                              hipStream_t stream)
{
    const float* x         = (const float*)d_in[0];
    const int*   edge_src  = (const int*)  d_in[1];
    const int*   edge_dst  = (const int*)  d_in[2];
    const float* edge_vals = (const float*)d_in[3];
    const float* weight    = (const float*)d_in[4];
    const float* bias      = (const float*)d_in[5];
    float*       out       = (float*)d_out;

    const int n_nodes = in_sizes[0] / D_IN;   // 50000
    const int n_edges = in_sizes[1];          // 800000

    // Workspace layout: h [n_nodes*64 f32] | row_ptr [(n_nodes+1) i32]
    float* h       = (float*)d_ws;
    int*   row_ptr = (int*)((char*)d_ws + (size_t)n_nodes * D_OUT * sizeof(float));

    // 1) h = x @ W
    {
        dim3 grid((n_nodes + 63) / 64), block(256);
        hipLaunchKernelGGL(gemm_h_kernel, grid, block, 0, stream, x, weight, h, n_nodes);
    }
    // 2) row_ptr from sorted edge_dst
    {
        dim3 grid((n_edges + 255) / 256), block(256);
        hipLaunchKernelGGL(build_row_ptr_kernel, grid, block, 0, stream,
                           edge_dst, row_ptr, n_edges, n_nodes);
    }
    // 3) aggregate + bias
    {
        dim3 grid((n_nodes + 3) / 4), block(256);   // 4 waves/block, 1 wave/node
        hipLaunchKernelGGL(aggregate_kernel, grid, block, 0, stream,
                           h, edge_src, edge_vals, row_ptr, bias, out, n_nodes);
    }
}

// Round 2
// 138.243 us; speedup vs baseline: 3.0318x; 3.0318x over previous
//
#include <hip/hip_runtime.h>

// Problem constants (GraphConvolution_71923522339430)
#define D_IN  128
#define D_OUT 64

// ---------------------------------------------------------------------------
// Kernel 1: h = x @ W   ([N,128] @ [128,64] -> [N,64], f32)
// Block = 256 threads, 64 nodes per block.
// LDS: Xs[64][132] (pad 132 so the 4-distinct-row broadcast reads land in
// different banks; 132*4 % 16 == 0 keeps float4 staging aligned),
// Ws[128][64] unpadded (each k-row float4 read spans 256 contiguous bytes ->
// 2-way bank aliasing only, which is free on gfx950).
// Thread (tx,ty): tx in [0,16) owns dims tx*4..+3; ty in [0,16) owns nodes
// ty*4..+3. 4x4 register tile.
// k-loop steps by 2 with unroll 2 only — round-1 full unroll spilled to
// scratch (VGPR=256, 800 MB of HBM spill traffic, 300 us). launch_bounds
// (256,4) caps the allocator at 128 VGPRs as insurance.
// ---------------------------------------------------------------------------
__global__ __launch_bounds__(256, 4) void gemm_h_kernel(
    const float* __restrict__ x, const float* __restrict__ w,
    float* __restrict__ h, int n_nodes)
{
    __shared__ float Xs[64 * 132];   // 33792 B
    __shared__ float Ws[128 * 64];   // 32768 B

    const int t   = threadIdx.x;
    const int tx  = t & 15;          // dim group
    const int ty  = t >> 4;          // node group
    const int node0 = blockIdx.x * 64;

    // Stage W: 2048 float4, 8 per thread. Coalesced global, aligned LDS.
    #pragma unroll
    for (int j = 0; j < 8; ++j) {
        int idx = j * 256 + t;           // float4 index
        int k   = idx >> 4;              // row (16 float4 per 64-float row)
        int c   = idx & 15;              // float4 col
        float4 v = *(const float4*)&w[k * D_OUT + c * 4];
        *(float4*)&Ws[k * 64 + c * 4] = v;
    }
    // Stage X tile: 64 rows x 128 floats = 2048 float4, 8 per thread.
    #pragma unroll
    for (int j = 0; j < 8; ++j) {
        int idx = j * 256 + t;
        int r   = idx >> 5;              // node row (32 float4 per row)
        int c   = idx & 31;
        int gn  = node0 + r;
        float4 v = make_float4(0.f, 0.f, 0.f, 0.f);
        if (gn < n_nodes) v = *(const float4*)&x[(size_t)gn * D_IN + c * 4];
        *(float4*)&Xs[r * 132 + c * 4] = v;
    }
    __syncthreads();

    float4 acc[4];
    #pragma unroll
    for (int i = 0; i < 4; ++i) acc[i] = make_float4(0.f, 0.f, 0.f, 0.f);

    const int d0 = tx * 4;
    const int n0 = ty * 4;

    #pragma unroll 2
    for (int k = 0; k < D_IN; k += 2) {
        float4 wb0 = *(const float4*)&Ws[k * 64 + d0];
        float4 wb1 = *(const float4*)&Ws[(k + 1) * 64 + d0];
        float2 xa[4];
        #pragma unroll
        for (int i = 0; i < 4; ++i)
            xa[i] = *(const float2*)&Xs[(n0 + i) * 132 + k];
        #pragma unroll
        for (int i = 0; i < 4; ++i) {
            acc[i].x = fmaf(xa[i].x, wb0.x, acc[i].x);
            acc[i].y = fmaf(xa[i].x, wb0.y, acc[i].y);
            acc[i].z = fmaf(xa[i].x, wb0.z, acc[i].z);
            acc[i].w = fmaf(xa[i].x, wb0.w, acc[i].w);
            acc[i].x = fmaf(xa[i].y, wb1.x, acc[i].x);
            acc[i].y = fmaf(xa[i].y, wb1.y, acc[i].y);
            acc[i].z = fmaf(xa[i].y, wb1.z, acc[i].z);
            acc[i].w = fmaf(xa[i].y, wb1.w, acc[i].w);
        }
    }

    #pragma unroll
    for (int i = 0; i < 4; ++i) {
        int gn = node0 + n0 + i;
        if (gn < n_nodes)
            *(float4*)&h[(size_t)gn * D_OUT + d0] = acc[i];
    }
}

// ---------------------------------------------------------------------------
// Kernel 2: build CSR row_ptr from sorted edge_dst.
// row_ptr[j] = first edge index with dst >= j; row_ptr[N] = E.
// ---------------------------------------------------------------------------
__global__ __launch_bounds__(256) void build_row_ptr_kernel(
    const int* __restrict__ dst, int* __restrict__ row_ptr, int n_edges, int n_nodes)
{
    int e = blockIdx.x * blockDim.x + threadIdx.x;
    if (e >= n_edges) return;
    int d1 = dst[e];
    int d0 = (e == 0) ? -1 : dst[e - 1];
    for (int j = d0 + 1; j <= d1; ++j) row_ptr[j] = e;
    if (e == n_edges - 1) {
        for (int j = d1 + 1; j <= n_nodes; ++j) row_ptr[j] = n_edges;
    }
}

// ---------------------------------------------------------------------------
// Kernel 3: out[i][d] = bias[d] + sum_{e in [row_ptr[i],row_ptr[i+1])}
//                       vals[e] * h[src[e]][d]
// One wave (64 lanes == D_OUT) per node. Broadcast src/val loads (uniform
// address -> single transaction), coalesced 256B h-row loads. 4x unroll for
// memory-level parallelism on the gather (latency-bound on L2/LLC hits).
// ---------------------------------------------------------------------------
__global__ __launch_bounds__(256) void aggregate_kernel(
    const float* __restrict__ h, const int* __restrict__ src,
    const float* __restrict__ vals, const int* __restrict__ row_ptr,
    const float* __restrict__ bias, float* __restrict__ out, int n_nodes)
{
    int wave = (blockIdx.x * blockDim.x + threadIdx.x) >> 6;
    int lane = threadIdx.x & 63;
    if (wave >= n_nodes) return;

    int b = row_ptr[wave];
    int e = row_ptr[wave + 1];

    float acc = 0.f;
    int k = b;
    for (; k + 3 < e; k += 4) {
        int   s0 = src[k],      s1 = src[k + 1];
        int   s2 = src[k + 2],  s3 = src[k + 3];
        float v0 = vals[k],     v1 = vals[k + 1];
        float v2 = vals[k + 2], v3 = vals[k + 3];
        float h0 = h[(size_t)s0 * D_OUT + lane];
        float h1 = h[(size_t)s1 * D_OUT + lane];
        float h2 = h[(size_t)s2 * D_OUT + lane];
        float h3 = h[(size_t)s3 * D_OUT + lane];
        acc = fmaf(v0, h0, acc);
        acc = fmaf(v1, h1, acc);
        acc = fmaf(v2, h2, acc);
        acc = fmaf(v3, h3, acc);
    }
    for (; k < e; ++k) {
        int   s0 = src[k];
        float v0 = vals[k];
        acc = fmaf(v0, h[(size_t)s0 * D_OUT + lane], acc);
    }

    out[(size_t)wave * D_OUT + lane] = acc + bias[lane];
}

// ---------------------------------------------------------------------------
extern "C" void kernel_launch(void* const* d_in, const int* in_sizes, int n_in,
                              void* d_out, int out_size, void* d_ws, size_t ws_size,
                              hipStream_t stream)
{
    const float* x         = (const float*)d_in[0];
    const int*   edge_src  = (const int*)  d_in[1];
    const int*   edge_dst  = (const int*)  d_in[2];
    const float* edge_vals = (const float*)d_in[3];
    const float* weight    = (const float*)d_in[4];
    const float* bias      = (const float*)d_in[5];
    float*       out       = (float*)d_out;

    const int n_nodes = in_sizes[0] / D_IN;   // 50000
    const int n_edges = in_sizes[1];          // 800000

    // Workspace layout: h [n_nodes*64 f32] | row_ptr [(n_nodes+1) i32]
    float* h       = (float*)d_ws;
    int*   row_ptr = (int*)((char*)d_ws + (size_t)n_nodes * D_OUT * sizeof(float));

    // 1) h = x @ W
    {
        dim3 grid((n_nodes + 63) / 64), block(256);
        hipLaunchKernelGGL(gemm_h_kernel, grid, block, 0, stream, x, weight, h, n_nodes);
    }
    // 2) row_ptr from sorted edge_dst
    {
        dim3 grid((n_edges + 255) / 256), block(256);
        hipLaunchKernelGGL(build_row_ptr_kernel, grid, block, 0, stream,
                           edge_dst, row_ptr, n_edges, n_nodes);
    }
    // 3) aggregate + bias
    {
        dim3 grid((n_nodes + 3) / 4), block(256);   // 4 waves/block, 1 wave/node
        hipLaunchKernelGGL(aggregate_kernel, grid, block, 0, stream,
                           h, edge_src, edge_vals, row_ptr, bias, out, n_nodes);
    }
}

// Round 3
// 129.342 us; speedup vs baseline: 3.2404x; 1.0688x over previous
//
#include <hip/hip_runtime.h>

// Problem constants (GraphConvolution_71923522339430)
#define D_IN  128
#define D_OUT 64

// ---------------------------------------------------------------------------
// Kernel 1: h = x @ W   ([N,128] @ [128,64] -> [N,64], f32)
// Block = 256 threads, 64 nodes per block. 4x4 register tile per thread.
// Inner loop: k-quads, all LDS reads are ds_read_b128 (round-2 was b64 X
// reads -> LDS-issue-bound ~3.5x; b128 makes the block LDS time ~3.1K cyc
// vs 4.1K cyc VALU -> VALU-bound).
// Xs stride 132: rows n0..n0+3 hit dword banks 4r..4r+3 -> conflict-free
// broadcast; 132*4B is 16B-aligned so float4 reads are legal.
// launch_bounds(256,4) caps VGPR at 128 (round-1 spill insurance).
// ---------------------------------------------------------------------------
__global__ __launch_bounds__(256, 4) void gemm_h_kernel(
    const float* __restrict__ x, const float* __restrict__ w,
    float* __restrict__ h, int n_nodes)
{
    __shared__ float Xs[64 * 132];   // 33792 B
    __shared__ float Ws[128 * 64];   // 32768 B

    const int t   = threadIdx.x;
    const int tx  = t & 15;          // dim group
    const int ty  = t >> 4;          // node group
    const int node0 = blockIdx.x * 64;

    // Stage W: 2048 float4, 8 per thread.
    #pragma unroll
    for (int j = 0; j < 8; ++j) {
        int idx = j * 256 + t;
        int k   = idx >> 4;
        int c   = idx & 15;
        float4 v = *(const float4*)&w[k * D_OUT + c * 4];
        *(float4*)&Ws[k * 64 + c * 4] = v;
    }
    // Stage X tile: 64 rows x 128 floats.
    #pragma unroll
    for (int j = 0; j < 8; ++j) {
        int idx = j * 256 + t;
        int r   = idx >> 5;
        int c   = idx & 31;
        int gn  = node0 + r;
        float4 v = make_float4(0.f, 0.f, 0.f, 0.f);
        if (gn < n_nodes) v = *(const float4*)&x[(size_t)gn * D_IN + c * 4];
        *(float4*)&Xs[r * 132 + c * 4] = v;
    }
    __syncthreads();

    float4 acc[4];
    #pragma unroll
    for (int i = 0; i < 4; ++i) acc[i] = make_float4(0.f, 0.f, 0.f, 0.f);

    const int d0 = tx * 4;
    const int n0 = ty * 4;

    #pragma unroll 2
    for (int k = 0; k < D_IN; k += 4) {
        float4 xa[4], wb[4];
        #pragma unroll
        for (int i = 0; i < 4; ++i)
            xa[i] = *(const float4*)&Xs[(n0 + i) * 132 + k];
        #pragma unroll
        for (int r = 0; r < 4; ++r)
            wb[r] = *(const float4*)&Ws[(k + r) * 64 + d0];
        #pragma unroll
        for (int i = 0; i < 4; ++i) {
            acc[i].x = fmaf(xa[i].x, wb[0].x, acc[i].x);
            acc[i].y = fmaf(xa[i].x, wb[0].y, acc[i].y);
            acc[i].z = fmaf(xa[i].x, wb[0].z, acc[i].z);
            acc[i].w = fmaf(xa[i].x, wb[0].w, acc[i].w);
            acc[i].x = fmaf(xa[i].y, wb[1].x, acc[i].x);
            acc[i].y = fmaf(xa[i].y, wb[1].y, acc[i].y);
            acc[i].z = fmaf(xa[i].y, wb[1].z, acc[i].z);
            acc[i].w = fmaf(xa[i].y, wb[1].w, acc[i].w);
            acc[i].x = fmaf(xa[i].z, wb[2].x, acc[i].x);
            acc[i].y = fmaf(xa[i].z, wb[2].y, acc[i].y);
            acc[i].z = fmaf(xa[i].z, wb[2].z, acc[i].z);
            acc[i].w = fmaf(xa[i].z, wb[2].w, acc[i].w);
            acc[i].x = fmaf(xa[i].w, wb[3].x, acc[i].x);
            acc[i].y = fmaf(xa[i].w, wb[3].y, acc[i].y);
            acc[i].z = fmaf(xa[i].w, wb[3].z, acc[i].z);
            acc[i].w = fmaf(xa[i].w, wb[3].w, acc[i].w);
        }
    }

    #pragma unroll
    for (int i = 0; i < 4; ++i) {
        int gn = node0 + n0 + i;
        if (gn < n_nodes)
            *(float4*)&h[(size_t)gn * D_OUT + d0] = acc[i];
    }
}

// ---------------------------------------------------------------------------
// Kernel 2: build CSR row_ptr from sorted edge_dst.
// ---------------------------------------------------------------------------
__global__ __launch_bounds__(256) void build_row_ptr_kernel(
    const int* __restrict__ dst, int* __restrict__ row_ptr, int n_edges, int n_nodes)
{
    int e = blockIdx.x * blockDim.x + threadIdx.x;
    if (e >= n_edges) return;
    int d1 = dst[e];
    int d0 = (e == 0) ? -1 : dst[e - 1];
    for (int j = d0 + 1; j <= d1; ++j) row_ptr[j] = e;
    if (e == n_edges - 1) {
        for (int j = d1 + 1; j <= n_nodes; ++j) row_ptr[j] = n_edges;
    }
}

// ---------------------------------------------------------------------------
// Kernel 3: out[i][:] = bias + sum_e vals[e] * h[src[e]][:]
// One wave per node, restructured from round-2:
//   lane = (sub = lane>>4) edge slot  x  (d4 = lane&15) float4 dim chunk.
// Each instruction gathers 4 edges' h rows as float4 (16 lanes x 16B = one
// 256B row per edge slot). 2x unroll -> 8 gathers in flight per wave
// (round-2: 4 x dword gathers, 1 edge per instr). Cross-sub reduction via
// __shfl_xor(16|32); lanes 0-15 store the float4 result + bias.
// ---------------------------------------------------------------------------
__global__ __launch_bounds__(256) void aggregate_kernel(
    const float4* __restrict__ h4, const int* __restrict__ src,
    const float* __restrict__ vals, const int* __restrict__ row_ptr,
    const float* __restrict__ bias, float* __restrict__ out, int n_nodes)
{
    int wave = (blockIdx.x * blockDim.x + threadIdx.x) >> 6;
    int lane = threadIdx.x & 63;
    if (wave >= n_nodes) return;
    int sub = lane >> 4;      // edge slot 0..3
    int d4  = lane & 15;      // float4 chunk of the 64-dim row

    int b = row_ptr[wave];
    int e = row_ptr[wave + 1];

    float4 acc = make_float4(0.f, 0.f, 0.f, 0.f);
    int k = b + sub;
    for (; k + 4 < e; k += 8) {
        int   s0 = src[k];     float v0 = vals[k];
        int   s1 = src[k + 4]; float v1 = vals[k + 4];
        float4 h0 = h4[(size_t)s0 * 16 + d4];
        float4 h1 = h4[(size_t)s1 * 16 + d4];
        acc.x = fmaf(v0, h0.x, acc.x);
        acc.y = fmaf(v0, h0.y, acc.y);
        acc.z = fmaf(v0, h0.z, acc.z);
        acc.w = fmaf(v0, h0.w, acc.w);
        acc.x = fmaf(v1, h1.x, acc.x);
        acc.y = fmaf(v1, h1.y, acc.y);
        acc.z = fmaf(v1, h1.z, acc.z);
        acc.w = fmaf(v1, h1.w, acc.w);
    }
    if (k < e) {
        int   s0 = src[k];
        float v0 = vals[k];
        float4 h0 = h4[(size_t)s0 * 16 + d4];
        acc.x = fmaf(v0, h0.x, acc.x);
        acc.y = fmaf(v0, h0.y, acc.y);
        acc.z = fmaf(v0, h0.z, acc.z);
        acc.w = fmaf(v0, h0.w, acc.w);
    }

    // Sum across the 4 edge slots (lanes differing in bits 4,5).
    #pragma unroll
    for (int off = 16; off < 64; off <<= 1) {
        acc.x += __shfl_xor(acc.x, off, 64);
        acc.y += __shfl_xor(acc.y, off, 64);
        acc.z += __shfl_xor(acc.z, off, 64);
        acc.w += __shfl_xor(acc.w, off, 64);
    }

    if (sub == 0) {
        float4 bb = *(const float4*)&bias[d4 * 4];
        float4 o;
        o.x = acc.x + bb.x;
        o.y = acc.y + bb.y;
        o.z = acc.z + bb.z;
        o.w = acc.w + bb.w;
        *(float4*)&out[(size_t)wave * D_OUT + d4 * 4] = o;
    }
}

// ---------------------------------------------------------------------------
extern "C" void kernel_launch(void* const* d_in, const int* in_sizes, int n_in,
                              void* d_out, int out_size, void* d_ws, size_t ws_size,
                              hipStream_t stream)
{
    const float* x         = (const float*)d_in[0];
    const int*   edge_src  = (const int*)  d_in[1];
    const int*   edge_dst  = (const int*)  d_in[2];
    const float* edge_vals = (const float*)d_in[3];
    const float* weight    = (const float*)d_in[4];
    const float* bias      = (const float*)d_in[5];
    float*       out       = (float*)d_out;

    const int n_nodes = in_sizes[0] / D_IN;   // 50000
    const int n_edges = in_sizes[1];          // 800000

    // Workspace layout: h [n_nodes*64 f32] | row_ptr [(n_nodes+1) i32]
    float* h       = (float*)d_ws;
    int*   row_ptr = (int*)((char*)d_ws + (size_t)n_nodes * D_OUT * sizeof(float));

    // 1) h = x @ W
    {
        dim3 grid((n_nodes + 63) / 64), block(256);
        hipLaunchKernelGGL(gemm_h_kernel, grid, block, 0, stream, x, weight, h, n_nodes);
    }
    // 2) row_ptr from sorted edge_dst
    {
        dim3 grid((n_edges + 255) / 256), block(256);
        hipLaunchKernelGGL(build_row_ptr_kernel, grid, block, 0, stream,
                           edge_dst, row_ptr, n_edges, n_nodes);
    }
    // 3) aggregate + bias
    {
        dim3 grid((n_nodes + 3) / 4), block(256);   // 4 waves/block, 1 wave/node
        hipLaunchKernelGGL(aggregate_kernel, grid, block, 0, stream,
                           (const float4*)h, edge_src, edge_vals, row_ptr, bias, out, n_nodes);
    }
}